// Round 4
// baseline (97.402 us; speedup 1.0000x reference)
//
#include <hip/hip_runtime.h>

// B=8192, J=17, F=128. f32 in/out.
// ws layout (float index):
//   [0, 32768)        : 128 slots x (128 sum + 128 sumsq) BN partials (memset 0 per launch)
//   [32768, 33024)    : stats: scale[128], shift[128]
//   [33024, 33313)    : off_sym[17*17]
//   [33313, 33330)    : diag[17]
//   [33344, 49728)    : W^T bf16 [256 cols][128 k] = 32768 shorts = 16384 floats (64KB)
//   [49728, ...)      : (if ws_size allows) bf16 pre-BN activations [139264*128]
// R3 BUG: OFF_PRE was 41536 -> pre clobbered wbt cols 128..255 (all of W[1]).

#define NSLOT      128
#define OFF_PART   0
#define OFF_STATS  32768
#define OFF_OFFSYM 33024
#define OFF_DIAG   33313
#define OFF_WBT    33344
#define OFF_PRE    49728
#define PRE_SHORTS (139264ull * 128ull)

typedef __attribute__((ext_vector_type(8))) short bf16x8;
typedef __attribute__((ext_vector_type(4))) short bf16x4;
typedef __attribute__((ext_vector_type(4))) float f32x4;

__device__ __forceinline__ short f2bf(float f) {
    unsigned u = __float_as_uint(f);
    u += 0x7FFFu + ((u >> 16) & 1u);   // round-to-nearest-even
    return (short)(u >> 16);
}
__device__ __forceinline__ float bf2f(short h) {
    return __uint_as_float(((unsigned)(unsigned short)h) << 16);
}
__device__ __forceinline__ float bflo(int p) {   // low bf16 of packed dword
    return __uint_as_float(((unsigned)p) << 16);
}
__device__ __forceinline__ float bfhi(int p) {   // high bf16 of packed dword
    return __uint_as_float(((unsigned)p) & 0xFFFF0000u);
}

// ---------------- prep: adjacency symmetrize + W transpose to bf16 ----------------
__global__ __launch_bounds__(256) void prep_kernel(
    const float* __restrict__ W, const float* __restrict__ adj,
    const float* __restrict__ adj2, float* __restrict__ wsf)
{
    const int t = threadIdx.x;            // 0..255
    short* wbt = (short*)(wsf + OFF_WBT);
    const int sel = t >> 7, np = t & 127;
    const float* wsrc = W + sel * 16384 + np;   // W[sel][k][np]
    #pragma unroll 8
    for (int k = 0; k < 128; ++k)
        wbt[t * 128 + k] = f2bf(wsrc[k * 128]); // WbfT[col][k]
    for (int e = t; e < 289; e += 256) {
        int i = e / 17, j = e % 17;
        float v = 0.5f * (adj[i*17+j] + adj2[i*17+j] + adj[j*17+i] + adj2[j*17+i]);
        if (i == j) { wsf[OFF_DIAG + i] = v; v = 0.f; }
        wsf[OFF_OFFSYM + i*17 + j] = v;
    }
}

// ---------------- conv: 2 batches (34 rows) per block, MFMA bf16 ----------------
// LDS union U: phase1 A-tile (48x136 shorts = 3264 ints), phase2 packed hh
// (34x140 ints, col<128 used), phase3 red[1024] floats. offs[] separate.
template<int USE_BF16>
__global__ __launch_bounds__(512, 8) void conv_kernel(
    const float* __restrict__ x, const float* __restrict__ M,
    const float* __restrict__ bias, float* ws,
    float* __restrict__ out, short* __restrict__ pre)
{
    __shared__ int U[34 * 140];
    __shared__ float offs[292];
    short (*A)[136] = (short(*)[136])U;
    int* hhI = U;

    const int tid = threadIdx.x;
    const int w = tid >> 6, l = tid & 63, c = l & 15, g = l >> 4;

    for (int e = tid; e < 289; e += 512) offs[e] = ws[OFF_OFFSYM + e];

    // ---- stage x[blk*34 .. +34) f32 -> bf16 LDS (1088 float4) ----
    const float4* xsrc = (const float4*)(x + (size_t)blockIdx.x * (34 * 128));
    #pragma unroll
    for (int it = 0; it < 3; ++it) {
        int f = tid + it * 512;
        if (f < 1088) {
            float4 v = xsrc[f];
            int r = f >> 5, k0 = (f & 31) << 2;
            bf16x4 p;
            p[0] = f2bf(v.x); p[1] = f2bf(v.y); p[2] = f2bf(v.z); p[3] = f2bf(v.w);
            *(bf16x4*)&A[r][k0] = p;
        }
    }
    if (tid < 476) {                       // zero pad rows 34..47 (14*136 shorts)
        bf16x4 z = {0, 0, 0, 0};
        ((bf16x4*)&A[34][0])[tid] = z;
    }
    __syncthreads();

    // ---- K-loop: wave w owns channel group col = w*16+c, both h0 and h1 ----
    const short* wbt = (const short*)(ws + OFF_WBT);
    const int col = w * 16 + c;
    f32x4 acc0[3], acc1[3];
    #pragma unroll
    for (int mt = 0; mt < 3; ++mt) {
        acc0[mt] = (f32x4){0.f, 0.f, 0.f, 0.f};
        acc1[mt] = (f32x4){0.f, 0.f, 0.f, 0.f};
    }
    #pragma unroll
    for (int ks = 0; ks < 4; ++ks) {
        bf16x8 b0 = *(const bf16x8*)(wbt + col * 128 + ks * 32 + g * 8);
        bf16x8 b1 = *(const bf16x8*)(wbt + (col + 128) * 128 + ks * 32 + g * 8);
        #pragma unroll
        for (int mt = 0; mt < 3; ++mt) {
            bf16x8 af = *(const bf16x8*)&A[mt * 16 + c][ks * 32 + g * 8];
            acc0[mt] = __builtin_amdgcn_mfma_f32_16x16x32_bf16(af, b0, acc0[mt], 0, 0, 0);
            acc1[mt] = __builtin_amdgcn_mfma_f32_16x16x32_bf16(af, b1, acc1[mt], 0, 0, 0);
        }
    }
    __syncthreads();   // all A reads done before hh overwrites U

    // ---- epilogue: fold diag/M/bias, pack (hh0,hh1) one dword per (row,col) ----
    const float bv = bias[col];
    #pragma unroll
    for (int mt = 0; mt < 3; ++mt) {
        #pragma unroll
        for (int r = 0; r < 4; ++r) {
            int row = mt * 16 + g * 4 + r;
            if (row < 34) {
                int j = row - 17 * ((row * 241) >> 12);   // row mod 17
                float m  = M[j * 128 + col];
                float dg = ws[OFF_DIAG + j];
                float lo = fmaf(dg * m, acc0[mt][r], bv); // diag*M*h0 + bias
                float hi = m * acc1[mt][r];               // M*h1
                unsigned pk = ((unsigned)(unsigned short)f2bf(lo)) |
                              (((unsigned)(unsigned short)f2bf(hi)) << 16);
                hhI[row * 140 + col] = (int)pk;
            }
        }
    }
    __syncthreads();   // hh ready

    // ---- mixing: tid -> (half, bb, o); rows split 9/8 across halves ----
    const int half = tid >> 8, bb = (tid >> 7) & 1, o = tid & 127;
    const int rb = bb * 17;
    int pj[17];
    #pragma unroll
    for (int i = 0; i < 17; ++i) pj[i] = hhI[(rb + i) * 140 + o];
    __syncthreads();   // pj reads done; U reusable as red

    float s = 0.f, s2 = 0.f;
    const size_t gbase = ((size_t)blockIdx.x * 34 + rb) * 128 + o;
    if (half == 0) {
        float vout[9];
        #pragma unroll
        for (int q = 0; q < 9; ++q) vout[q] = bflo(pj[q]);
        #pragma unroll
        for (int j = 0; j < 17; ++j) {
            float h1v = bfhi(pj[j]);
            #pragma unroll
            for (int q = 0; q < 9; ++q)
                vout[q] = fmaf(offs[q * 17 + j], h1v, vout[q]);
        }
        #pragma unroll
        for (int q = 0; q < 9; ++q) {
            float v = vout[q];
            if (USE_BF16) pre[gbase + (size_t)q * 128] = f2bf(v);
            else          out[gbase + (size_t)q * 128] = v;
            s += v; s2 = fmaf(v, v, s2);
        }
    } else {
        float vout[8];
        #pragma unroll
        for (int q = 0; q < 8; ++q) vout[q] = bflo(pj[9 + q]);
        #pragma unroll
        for (int j = 0; j < 17; ++j) {
            float h1v = bfhi(pj[j]);
            #pragma unroll
            for (int q = 0; q < 8; ++q)
                vout[q] = fmaf(offs[(9 + q) * 17 + j], h1v, vout[q]);
        }
        #pragma unroll
        for (int q = 0; q < 8; ++q) {
            float v = vout[q];
            if (USE_BF16) pre[gbase + (size_t)(9 + q) * 128] = f2bf(v);
            else          out[gbase + (size_t)(9 + q) * 128] = v;
            s += v; s2 = fmaf(v, v, s2);
        }
    }

    // ---- BN partials: block LDS reduce (in U) then 256 lane-atomics ----
    float* red = (float*)U;
    red[tid] = s; red[512 + tid] = s2;
    __syncthreads();
    if (tid < 128) {
        float ts = red[tid] + red[tid + 128] + red[tid + 256] + red[tid + 384];
        float t2 = red[512 + tid] + red[512 + tid + 128] +
                   red[512 + tid + 256] + red[512 + tid + 384];
        float* slot = ws + OFF_PART + ((blockIdx.x & (NSLOT - 1)) << 8);
        atomicAdd(slot + tid, ts);
        atomicAdd(slot + 128 + tid, t2);
    }
}

// ---------------- BN stats reduce ----------------
__global__ __launch_bounds__(256) void bn_reduce_kernel(
    const float* __restrict__ part, const float* __restrict__ gamma,
    const float* __restrict__ beta, float* __restrict__ stats)
{
    const int t = threadIdx.x;             // 0..255
    float s = 0.f;
    #pragma unroll 8
    for (int i = 0; i < NSLOT; ++i) s += part[i * 256 + t];
    __shared__ float tot[256];
    tot[t] = s;
    __syncthreads();
    if (t < 128) {
        const float n = 139264.f;          // 8192*17
        float mean = tot[t] / n;
        float var  = tot[t + 128] / n - mean * mean;
        var = fmaxf(var, 0.f);
        float inv = rsqrtf(var + 1e-5f);
        float sc = gamma[t] * inv;
        stats[t] = sc;
        stats[t + 128] = beta[t] - mean * sc;
    }
}

// ---------------- BN apply + relu: bf16 pre (ws) -> f32 out ----------------
__global__ __launch_bounds__(256) void apply_bf16_kernel(
    const short* __restrict__ pre, const float* __restrict__ stats,
    float* __restrict__ out)
{
    const int tid = blockIdx.x * 256 + threadIdx.x;
    const int c0 = (tid << 3) & 127;       // stride (524288*8) % 128 == 0
    float sc[8], sh[8];
    #pragma unroll
    for (int e = 0; e < 8; ++e) { sc[e] = stats[c0 + e]; sh[e] = stats[128 + c0 + e]; }
    const bf16x8* p8 = (const bf16x8*)pre;
    for (int q = tid; q < 2228224; q += 524288) {
        bf16x8 v = p8[q];
        float4 o0, o1;
        o0.x = fmaxf(fmaf(bf2f(v[0]), sc[0], sh[0]), 0.f);
        o0.y = fmaxf(fmaf(bf2f(v[1]), sc[1], sh[1]), 0.f);
        o0.z = fmaxf(fmaf(bf2f(v[2]), sc[2], sh[2]), 0.f);
        o0.w = fmaxf(fmaf(bf2f(v[3]), sc[3], sh[3]), 0.f);
        o1.x = fmaxf(fmaf(bf2f(v[4]), sc[4], sh[4]), 0.f);
        o1.y = fmaxf(fmaf(bf2f(v[5]), sc[5], sh[5]), 0.f);
        o1.z = fmaxf(fmaf(bf2f(v[6]), sc[6], sh[6]), 0.f);
        o1.w = fmaxf(fmaf(bf2f(v[7]), sc[7], sh[7]), 0.f);
        float4* dst = (float4*)(out + (size_t)q * 8);
        dst[0] = o0; dst[1] = o1;
    }
}

// ---------------- BN apply + relu fallback (in-place f32) ----------------
__global__ __launch_bounds__(256) void apply_kernel(
    float* __restrict__ out, const float* __restrict__ stats, int n4)
{
    const int tid = blockIdx.x * 256 + threadIdx.x;
    const int c0 = (tid << 2) & 127;
    const float sc0 = stats[c0],     sc1 = stats[c0 + 1],
                sc2 = stats[c0 + 2], sc3 = stats[c0 + 3];
    const float sh0 = stats[128 + c0],     sh1 = stats[128 + c0 + 1],
                sh2 = stats[128 + c0 + 2], sh3 = stats[128 + c0 + 3];
    float4* o4 = (float4*)out;
    for (int q = tid; q < n4; q += 2048 * 256) {
        float4 v = o4[q];
        v.x = fmaxf(fmaf(v.x, sc0, sh0), 0.f);
        v.y = fmaxf(fmaf(v.y, sc1, sh1), 0.f);
        v.z = fmaxf(fmaf(v.z, sc2, sh2), 0.f);
        v.w = fmaxf(fmaf(v.w, sc3, sh3), 0.f);
        o4[q] = v;
    }
}

extern "C" void kernel_launch(void* const* d_in, const int* in_sizes, int n_in,
                              void* d_out, int out_size, void* d_ws, size_t ws_size,
                              hipStream_t stream) {
    (void)in_sizes; (void)n_in; (void)out_size;
    const float* x     = (const float*)d_in[0];
    const float* W     = (const float*)d_in[1];
    const float* M     = (const float*)d_in[2];
    const float* adj   = (const float*)d_in[3];
    const float* adj2  = (const float*)d_in[4];
    const float* bias  = (const float*)d_in[5];
    const float* gamma = (const float*)d_in[6];
    const float* beta  = (const float*)d_in[7];
    float* out = (float*)d_out;
    float* wsf = (float*)d_ws;
    short* pre = (short*)(wsf + OFF_PRE);

    const bool big = ws_size >= (size_t)OFF_PRE * 4 + PRE_SHORTS * 2;

    hipMemsetAsync(d_ws, 0, NSLOT * 256 * sizeof(float), stream);   // BN partial slots
    prep_kernel<<<1, 256, 0, stream>>>(W, adj, adj2, wsf);
    if (big) {
        conv_kernel<1><<<4096, 512, 0, stream>>>(x, M, bias, wsf, out, pre);
        bn_reduce_kernel<<<1, 256, 0, stream>>>(wsf + OFF_PART, gamma, beta, wsf + OFF_STATS);
        apply_bf16_kernel<<<2048, 256, 0, stream>>>(pre, wsf + OFF_STATS, out);
    } else {
        conv_kernel<0><<<4096, 512, 0, stream>>>(x, M, bias, wsf, out, pre);
        bn_reduce_kernel<<<1, 256, 0, stream>>>(wsf + OFF_PART, gamma, beta, wsf + OFF_STATS);
        apply_kernel<<<2048, 256, 0, stream>>>(out, wsf + OFF_STATS, 4456448);
    }
}

// Round 5
// 96.096 us; speedup vs baseline: 1.0136x; 1.0136x over previous
//
#include <hip/hip_runtime.h>

// B=8192, J=17, F=128. f32 in/out.
// ws layout (float index):
//   [0, 32768)        : 128 slots x (128 sum + 128 sumsq) BN partials (memset 0 per launch)
//   [32768, 33024)    : stats: scale[128], shift[128]
//   [33024, 33313)    : off_sym[17*17]
//   [33313, 33330)    : diag[17]
//   [33344, 49728)    : W^T bf16 [256 cols][128 k] = 32768 shorts = 16384 floats (64KB)
//   [49728, ...)      : bf16 pre-BN activations [139264*128] (35.7MB) if ws_size allows

#define NSLOT      128
#define OFF_PART   0
#define OFF_STATS  32768
#define OFF_OFFSYM 33024
#define OFF_DIAG   33313
#define OFF_WBT    33344
#define OFF_PRE    49728
#define PRE_SHORTS (139264ull * 128ull)

typedef __attribute__((ext_vector_type(8))) short bf16x8;
typedef __attribute__((ext_vector_type(4))) short bf16x4;
typedef __attribute__((ext_vector_type(4))) float f32x4;

__device__ __forceinline__ short f2bf(float f) {
    unsigned u = __float_as_uint(f);
    u += 0x7FFFu + ((u >> 16) & 1u);   // round-to-nearest-even
    return (short)(u >> 16);
}
__device__ __forceinline__ float bf2f(short h) {
    return __uint_as_float(((unsigned)(unsigned short)h) << 16);
}
__device__ __forceinline__ float bflo(int p) {   // low bf16 of packed dword
    return __uint_as_float(((unsigned)p) << 16);
}
__device__ __forceinline__ float bfhi(int p) {   // high bf16 of packed dword
    return __uint_as_float(((unsigned)p) & 0xFFFF0000u);
}

// ---------------- prep: 17 blocks. blk0: adjacency; blk1..16: W^T bf16 ----------------
__global__ __launch_bounds__(256) void prep_kernel(
    const float* __restrict__ W, const float* __restrict__ adj,
    const float* __restrict__ adj2, float* __restrict__ wsf)
{
    const int t = threadIdx.x, b = blockIdx.x;
    if (b == 0) {
        for (int e = t; e < 289; e += 256) {
            int i = e / 17, j = e % 17;
            float v = 0.5f * (adj[i*17+j] + adj2[i*17+j] + adj[j*17+i] + adj2[j*17+i]);
            if (i == j) { wsf[OFF_DIAG + i] = v; v = 0.f; }
            wsf[OFF_OFFSYM + i*17 + j] = v;
        }
        return;
    }
    // 16 cols per block, 16 k-elems per thread-group of 16
    short* wbt = (short*)(wsf + OFF_WBT);
    const int col = (b - 1) * 16 + (t >> 4);
    const int k0  = (t & 15) * 8;
    const int sel = col >> 7, colp = col & 127;
    const float* src = W + sel * 16384 + colp;   // W[sel][k][colp]
    bf16x8 p;
    #pragma unroll
    for (int e = 0; e < 8; ++e) p[e] = f2bf(src[(k0 + e) * 128]);
    *(bf16x8*)(wbt + col * 128 + k0) = p;
}

// ---------------- conv: 4 batches (68 rows) per block, MFMA bf16, LDS union ----------
// U union: phase1 A-tile (80x136 shorts = 21.8KB), phase2 packed hh (68x130 ints =
// 35.4KB), phase3 red[1024] floats. offs[] separate. Total LDS ~36.6KB -> 4 blocks/CU.
template<int USE_BF16>
__global__ __launch_bounds__(512, 8) void conv_kernel(
    const float* __restrict__ x, const float* __restrict__ M,
    const float* __restrict__ bias, float* ws,
    float* __restrict__ out, short* __restrict__ pre)
{
    __shared__ int U[68 * 130];
    __shared__ float offs[292];
    short (*A)[136] = (short(*)[136])U;   // 80 rows (12 zero-pad), 136-short stride
    int* hhI = U;                          // 68 x 130 ints

    const int tid = threadIdx.x;
    const int w = tid >> 6, l = tid & 63, c = l & 15, g = l >> 4;

    for (int e = tid; e < 289; e += 512) offs[e] = ws[OFF_OFFSYM + e];

    // ---- stage x[blk*68 .. +68) f32 -> bf16 LDS (2176 float4) ----
    const float4* xsrc = (const float4*)(x + (size_t)blockIdx.x * (68 * 128));
    #pragma unroll
    for (int it = 0; it < 5; ++it) {
        int f = tid + it * 512;
        if (f < 2176) {
            float4 v = xsrc[f];
            int r = f >> 5, k0 = (f & 31) << 2;
            bf16x4 p;
            p[0] = f2bf(v.x); p[1] = f2bf(v.y); p[2] = f2bf(v.z); p[3] = f2bf(v.w);
            *(bf16x4*)&A[r][k0] = p;
        }
    }
    if (tid < 408) {                       // zero pad rows 68..79 (12*136 shorts)
        bf16x4 z = {0, 0, 0, 0};
        ((bf16x4*)&A[68][0])[tid] = z;
    }
    __syncthreads();

    // ---- K-loop: wave w owns col = w*16+c for both h0 (col) and h1 (col+128) ----
    const short* wbt = (const short*)(ws + OFF_WBT);
    const int col = w * 16 + c;
    f32x4 acc0[5], acc1[5];
    #pragma unroll
    for (int mt = 0; mt < 5; ++mt) {
        acc0[mt] = (f32x4){0.f, 0.f, 0.f, 0.f};
        acc1[mt] = (f32x4){0.f, 0.f, 0.f, 0.f};
    }
    #pragma unroll
    for (int ks = 0; ks < 4; ++ks) {
        bf16x8 b0 = *(const bf16x8*)(wbt + col * 128 + ks * 32 + g * 8);
        bf16x8 b1 = *(const bf16x8*)(wbt + (col + 128) * 128 + ks * 32 + g * 8);
        #pragma unroll
        for (int mt = 0; mt < 5; ++mt) {
            bf16x8 af = *(const bf16x8*)&A[mt * 16 + c][ks * 32 + g * 8];
            acc0[mt] = __builtin_amdgcn_mfma_f32_16x16x32_bf16(af, b0, acc0[mt], 0, 0, 0);
            acc1[mt] = __builtin_amdgcn_mfma_f32_16x16x32_bf16(af, b1, acc1[mt], 0, 0, 0);
        }
    }
    __syncthreads();   // all A reads done before hh overwrites U

    // ---- epilogue: fold diag/M/bias, pack (hh0,hh1) one dword per (row,col) ----
    const float bv = bias[col];
    #pragma unroll
    for (int mt = 0; mt < 5; ++mt) {
        #pragma unroll
        for (int r = 0; r < 4; ++r) {
            int row = mt * 16 + g * 4 + r;
            if (row < 68) {
                int j = row - 17 * ((row * 241) >> 12);   // row % 17 (valid to 67)
                float m  = M[j * 128 + col];
                float dg = ws[OFF_DIAG + j];
                float lo = fmaf(dg * m, acc0[mt][r], bv); // diag*M*h0 + bias
                float hi = m * acc1[mt][r];               // M*h1
                unsigned pk = ((unsigned)(unsigned short)f2bf(lo)) |
                              (((unsigned)(unsigned short)f2bf(hi)) << 16);
                hhI[row * 130 + col] = (int)pk;
            }
        }
    }
    __syncthreads();   // hh ready

    // ---- mixing: thread -> (bb = tid>>7, o = tid&127); full 17 rows each ----
    const int bb = tid >> 7, o = tid & 127;
    const int rb = bb * 17;
    int pj[17];
    #pragma unroll
    for (int i = 0; i < 17; ++i) pj[i] = hhI[(rb + i) * 130 + o];
    __syncthreads();   // pj reads done; U reusable as red

    float vout[17];
    #pragma unroll
    for (int q = 0; q < 17; ++q) vout[q] = bflo(pj[q]);
    #pragma unroll
    for (int j = 0; j < 17; ++j) {
        float h1v = bfhi(pj[j]);
        #pragma unroll
        for (int q = 0; q < 17; ++q)
            vout[q] = fmaf(offs[q * 17 + j], h1v, vout[q]);
    }

    float s = 0.f, s2 = 0.f;
    const size_t gbase = ((size_t)blockIdx.x * 68 + rb) * 128 + o;
    #pragma unroll
    for (int q = 0; q < 17; ++q) {
        float v = vout[q];
        if (USE_BF16) pre[gbase + (size_t)q * 128] = f2bf(v);
        else          out[gbase + (size_t)q * 128] = v;
        s += v; s2 = fmaf(v, v, s2);
    }

    // ---- BN partials: block LDS reduce (in U) then 256 lane-atomics ----
    float* red = (float*)U;
    red[tid] = s; red[512 + tid] = s2;
    __syncthreads();
    if (tid < 128) {
        float ts = red[tid] + red[tid + 128] + red[tid + 256] + red[tid + 384];
        float t2 = red[512 + tid] + red[512 + tid + 128] +
                   red[512 + tid + 256] + red[512 + tid + 384];
        float* slot = ws + OFF_PART + ((blockIdx.x & (NSLOT - 1)) << 8);
        atomicAdd(slot + tid, ts);
        atomicAdd(slot + 128 + tid, t2);
    }
}

// ---------------- BN stats reduce ----------------
__global__ __launch_bounds__(256) void bn_reduce_kernel(
    const float* __restrict__ part, const float* __restrict__ gamma,
    const float* __restrict__ beta, float* __restrict__ stats)
{
    const int t = threadIdx.x;             // 0..255
    float s = 0.f;
    #pragma unroll 8
    for (int i = 0; i < NSLOT; ++i) s += part[i * 256 + t];
    __shared__ float tot[256];
    tot[t] = s;
    __syncthreads();
    if (t < 128) {
        const float n = 139264.f;          // 8192*17
        float mean = tot[t] / n;
        float var  = tot[t + 128] / n - mean * mean;
        var = fmaxf(var, 0.f);
        float inv = rsqrtf(var + 1e-5f);
        float sc = gamma[t] * inv;
        stats[t] = sc;
        stats[t + 128] = beta[t] - mean * sc;
    }
}

// ---------------- BN apply + relu: bf16 pre (ws) -> f32 out ----------------
__global__ __launch_bounds__(256) void apply_bf16_kernel(
    const short* __restrict__ pre, const float* __restrict__ stats,
    float* __restrict__ out)
{
    const int tid = blockIdx.x * 256 + threadIdx.x;
    const int c0 = (tid << 3) & 127;       // stride (524288*8) % 128 == 0
    float sc[8], sh[8];
    #pragma unroll
    for (int e = 0; e < 8; ++e) { sc[e] = stats[c0 + e]; sh[e] = stats[128 + c0 + e]; }
    const bf16x8* p8 = (const bf16x8*)pre;
    for (int q = tid; q < 2228224; q += 524288) {
        bf16x8 v = p8[q];
        float4 o0, o1;
        o0.x = fmaxf(fmaf(bf2f(v[0]), sc[0], sh[0]), 0.f);
        o0.y = fmaxf(fmaf(bf2f(v[1]), sc[1], sh[1]), 0.f);
        o0.z = fmaxf(fmaf(bf2f(v[2]), sc[2], sh[2]), 0.f);
        o0.w = fmaxf(fmaf(bf2f(v[3]), sc[3], sh[3]), 0.f);
        o1.x = fmaxf(fmaf(bf2f(v[4]), sc[4], sh[4]), 0.f);
        o1.y = fmaxf(fmaf(bf2f(v[5]), sc[5], sh[5]), 0.f);
        o1.z = fmaxf(fmaf(bf2f(v[6]), sc[6], sh[6]), 0.f);
        o1.w = fmaxf(fmaf(bf2f(v[7]), sc[7], sh[7]), 0.f);
        float4* dst = (float4*)(out + (size_t)q * 8);
        dst[0] = o0; dst[1] = o1;
    }
}

// ---------------- BN apply + relu fallback (in-place f32) ----------------
__global__ __launch_bounds__(256) void apply_kernel(
    float* __restrict__ out, const float* __restrict__ stats, int n4)
{
    const int tid = blockIdx.x * 256 + threadIdx.x;
    const int c0 = (tid << 2) & 127;
    const float sc0 = stats[c0],     sc1 = stats[c0 + 1],
                sc2 = stats[c0 + 2], sc3 = stats[c0 + 3];
    const float sh0 = stats[128 + c0],     sh1 = stats[128 + c0 + 1],
                sh2 = stats[128 + c0 + 2], sh3 = stats[128 + c0 + 3];
    float4* o4 = (float4*)out;
    for (int q = tid; q < n4; q += 2048 * 256) {
        float4 v = o4[q];
        v.x = fmaxf(fmaf(v.x, sc0, sh0), 0.f);
        v.y = fmaxf(fmaf(v.y, sc1, sh1), 0.f);
        v.z = fmaxf(fmaf(v.z, sc2, sh2), 0.f);
        v.w = fmaxf(fmaf(v.w, sc3, sh3), 0.f);
        o4[q] = v;
    }
}

extern "C" void kernel_launch(void* const* d_in, const int* in_sizes, int n_in,
                              void* d_out, int out_size, void* d_ws, size_t ws_size,
                              hipStream_t stream) {
    (void)in_sizes; (void)n_in; (void)out_size;
    const float* x     = (const float*)d_in[0];
    const float* W     = (const float*)d_in[1];
    const float* M     = (const float*)d_in[2];
    const float* adj   = (const float*)d_in[3];
    const float* adj2  = (const float*)d_in[4];
    const float* bias  = (const float*)d_in[5];
    const float* gamma = (const float*)d_in[6];
    const float* beta  = (const float*)d_in[7];
    float* out = (float*)d_out;
    float* wsf = (float*)d_ws;
    short* pre = (short*)(wsf + OFF_PRE);

    const bool big = ws_size >= (size_t)OFF_PRE * 4 + PRE_SHORTS * 2;

    hipMemsetAsync(d_ws, 0, NSLOT * 256 * sizeof(float), stream);   // BN partial slots
    prep_kernel<<<17, 256, 0, stream>>>(W, adj, adj2, wsf);
    if (big) {
        conv_kernel<1><<<2048, 512, 0, stream>>>(x, M, bias, wsf, out, pre);
        bn_reduce_kernel<<<1, 256, 0, stream>>>(wsf + OFF_PART, gamma, beta, wsf + OFF_STATS);
        apply_bf16_kernel<<<2048, 256, 0, stream>>>(pre, wsf + OFF_STATS, out);
    } else {
        conv_kernel<0><<<2048, 512, 0, stream>>>(x, M, bias, wsf, out, pre);
        bn_reduce_kernel<<<1, 256, 0, stream>>>(wsf + OFF_PART, gamma, beta, wsf + OFF_STATS);
        apply_kernel<<<2048, 256, 0, stream>>>(out, wsf + OFF_STATS, 4456448);
    }
}